// Round 8
// baseline (133.424 us; speedup 1.0000x reference)
//
#include <hip/hip_runtime.h>
#include <hip/hip_bf16.h>

typedef float f32x4 __attribute__((ext_vector_type(4)));
typedef short s16x8 __attribute__((ext_vector_type(8)));

__device__ __forceinline__ float leaky2(float x){ return fmaf(0.4f, fabsf(x), 0.6f * x); }

__device__ __forceinline__ short f2bf(float f){
    return __builtin_bit_cast(short, __float2bfloat16(f));
}

// ---------------------------------------------------------------------------
// K_cvt: bf16 copies + packed MFMA B-fragment layouts, ALL READS COALESCED
// (source-indexed; scattered writes combine in L2).
// Block gridDim-1 (=2048) instead runs the setup math (A, sparsity, DAG).
// ---------------------------------------------------------------------------
__global__ __launch_bounds__(256) void k_cvt(
    const float* __restrict__ feat, const float* __restrict__ ew1,
    const float* __restrict__ ew2, const float* __restrict__ dw2,
    const float* __restrict__ mw1, const float* __restrict__ mw2,
    short* __restrict__ featbf, short* __restrict__ w1p,
    short* __restrict__ ew2p, short* __restrict__ dw2p,
    short* __restrict__ mw1p, short* __restrict__ mw2p,
    const float* __restrict__ lw, float* __restrict__ A,
    float* __restrict__ acc)
{
    if (blockIdx.x >= 2048){
        // ---- setup: A matrix, sparsity, DAG (256 threads) ----
        __shared__ float A2s[1024], mp[1024], red[256];
        const int t = threadIdx.x;
        float part = 0.f;
        #pragma unroll
        for (int q = 0; q < 4; ++q){
            int e = t * 4 + q;
            int r = e >> 5, c = e & 31;
            float v = lw[e];
            float sig = 1.f / (1.f + expf(-v));
            float l2 = (r < c) ? v * 10.f : ((r == c) ? -100.f : 0.f);
            A[e] = 1.f / (1.f + expf(-l2));
            part += sig;
            float a2 = sig * sig;
            A2s[e] = a2; mp[e] = a2;
        }
        red[t] = part; __syncthreads();
        for (int s = 128; s > 0; s >>= 1){ if (t < s) red[t] += red[t + s]; __syncthreads(); }
        if (t == 0) acc[2] = red[0];

        const float invf[10] = {0.f, 1.f, 0.5f, 1.6666667e-1f, 4.1666667e-2f,
                                8.3333333e-3f, 1.3888889e-3f, 1.9841270e-4f,
                                2.4801587e-5f, 2.7557319e-6f};
        float tr = 0.f;
        const int r = t >> 3, c0 = (t & 7) * 4;
        for (int n = 1; n <= 9; ++n){
            __syncthreads();
            if (t == 0){
                float s = 0.f;
                for (int k2 = 0; k2 < 32; ++k2) s += mp[k2 * 33];
                tr += s * invf[n];
            }
            if (n == 9) break;
            float av[4] = {0.f, 0.f, 0.f, 0.f};
            for (int k2 = 0; k2 < 32; ++k2){
                float m = mp[r * 32 + k2];
                #pragma unroll
                for (int q = 0; q < 4; ++q) av[q] = fmaf(m, A2s[k2 * 32 + c0 + q], av[q]);
            }
            __syncthreads();
            #pragma unroll
            for (int q = 0; q < 4; ++q) mp[r * 32 + c0 + q] = av[q];
        }
        if (t == 0) acc[3] = tr * tr;
        return;
    }
    for (int idx = blockIdx.x * 256 + threadIdx.x; idx < 4947968; idx += 2048 * 256){
        if (idx < 2097152){ featbf[idx] = f2bf(feat[idx]); continue; }
        int s = idx - 2097152;
        if (s < 262144){                     // enc_w1 [512][512]
            int k = s >> 9, n = s & 511;
            int lane = (((k >> 3) & 3) << 4) | (n & 15);
            w1p[((n >> 4) * 16 + (k >> 5)) * 512 + lane * 8 + (k & 7)] = f2bf(ew1[s]);
            continue;
        }
        s -= 262144;
        if (s < 32768){                      // enc_w2 [512][64]
            int k = s >> 6, n = s & 63;
            int lane = (((k >> 3) & 3) << 4) | (n & 15);
            ew2p[((n >> 4) * 16 + (k >> 5)) * 512 + lane * 8 + (k & 7)] = f2bf(ew2[s]);
            continue;
        }
        s -= 32768;
        if (s < 262144){                     // dec_w2 [512][512]
            int k = s >> 9, n = s & 511;
            int lane = (((k >> 3) & 3) << 4) | (n & 15);
            dw2p[((n >> 4) * 16 + (k >> 5)) * 512 + lane * 8 + (k & 7)] = f2bf(dw2[s]);
            continue;
        }
        s -= 262144;
        if (s < 262144){                     // mech_w1 [32][32][256]
            int i = s >> 13, r2 = s & 8191;
            int k = r2 >> 8, n = r2 & 255;
            int lane = (((k >> 3) & 3) << 4) | (n & 15);
            mw1p[i * 8192 + (n >> 4) * 512 + lane * 8 + (k & 7)] = f2bf(mw1[s]);
            continue;
        }
        s -= 262144;                         // mi_w2 [496][64][64]
        int p = s >> 12, r2 = s & 4095;
        int k = r2 >> 6, n = r2 & 63;
        int lane = (((k >> 3) & 3) << 4) | (n & 15);
        mw2p[p * 4096 + ((n >> 4) * 2 + (k >> 5)) * 512 + lane * 8 + (k & 7)] = f2bf(mw2[s]);
    }
}

// ---------------------------------------------------------------------------
// K_genc: h = leaky(feat @ enc_w1 + b1), bf16 out. 32x128 tile, 4 waves.
// ---------------------------------------------------------------------------
__global__ __launch_bounds__(256) void k_genc(const short* __restrict__ Abf,
                                              const short* __restrict__ Bp,
                                              const float* __restrict__ bias,
                                              short* __restrict__ Hbf)
{
    const int lane = threadIdx.x & 63, wv = threadIdx.x >> 6;
    const int ml = lane & 15, kg = lane >> 4;
    const int b0 = blockIdx.x * 32 + (wv >> 1) * 16;
    const int c0 = blockIdx.y * 128 + (wv & 1) * 64;
    const int nt0 = c0 >> 4;
    f32x4 acc[4] = {};
    for (int kt = 0; kt < 16; ++kt){
        s16x8 a = *(const s16x8*)&Abf[(size_t)(b0 + ml) * 512 + kt * 32 + kg * 8];
        #pragma unroll
        for (int ni = 0; ni < 4; ++ni){
            s16x8 b = *(const s16x8*)&Bp[((nt0 + ni) * 16 + kt) * 512 + lane * 8];
            acc[ni] = __builtin_amdgcn_mfma_f32_16x16x32_bf16(a, b, acc[ni], 0, 0, 0);
        }
    }
    #pragma unroll
    for (int ni = 0; ni < 4; ++ni){
        int col = c0 + ni * 16 + ml;
        float bv = bias[col];
        #pragma unroll
        for (int r = 0; r < 4; ++r){
            int row = b0 + kg * 4 + r;
            Hbf[(size_t)row * 512 + col] = f2bf(leaky2(acc[ni][r] + bv));
        }
    }
}

// ---------------------------------------------------------------------------
// K_grec: recon = d1 @ dec_w2 + b2 (fp32 out) + recon-loss atomic. 32x128.
// ---------------------------------------------------------------------------
__global__ __launch_bounds__(256) void k_grec(const short* __restrict__ Abf,
                                              const short* __restrict__ Bp,
                                              const float* __restrict__ bias,
                                              const float* __restrict__ feat,
                                              float* __restrict__ recon,
                                              float* __restrict__ accg)
{
    __shared__ float red[256];
    const int t = threadIdx.x;
    const int lane = t & 63, wv = t >> 6;
    const int ml = lane & 15, kg = lane >> 4;
    const int b0 = blockIdx.x * 32 + (wv >> 1) * 16;
    const int c0 = blockIdx.y * 128 + (wv & 1) * 64;
    const int nt0 = c0 >> 4;
    f32x4 acc[4] = {};
    for (int kt = 0; kt < 16; ++kt){
        s16x8 a = *(const s16x8*)&Abf[(size_t)(b0 + ml) * 512 + kt * 32 + kg * 8];
        #pragma unroll
        for (int ni = 0; ni < 4; ++ni){
            s16x8 b = *(const s16x8*)&Bp[((nt0 + ni) * 16 + kt) * 512 + lane * 8];
            acc[ni] = __builtin_amdgcn_mfma_f32_16x16x32_bf16(a, b, acc[ni], 0, 0, 0);
        }
    }
    float lsum = 0.f;
    #pragma unroll
    for (int ni = 0; ni < 4; ++ni){
        int col = c0 + ni * 16 + ml;
        float bv = bias[col];
        #pragma unroll
        for (int r = 0; r < 4; ++r){
            int row = b0 + kg * 4 + r;
            float v = acc[ni][r] + bv;
            float d = v - feat[(size_t)row * 512 + col];
            lsum = fmaf(d, d, lsum);
            recon[(size_t)row * 512 + col] = v;
        }
    }
    red[t] = lsum; __syncthreads();
    for (int s = 128; s > 0; s >>= 1){ if (t < s) red[t] += red[t + s]; __syncthreads(); }
    if (t == 0) atomicAdd(accg + 1, red[0]);
}

// ---------------------------------------------------------------------------
// K_pmfma: params -> mean/std/z + KL; writes z TRANSPOSED zt[32][4096].
// ---------------------------------------------------------------------------
__global__ __launch_bounds__(256) void k_pmfma(const short* __restrict__ Hbf,
                                               const short* __restrict__ Bp,
                                               const float* __restrict__ b2,
                                               const float* __restrict__ eps,
                                               float* __restrict__ omean,
                                               float* __restrict__ ostd,
                                               float* __restrict__ zt,
                                               float* __restrict__ accg)
{
    __shared__ float P[16][65];
    __shared__ float zs[16][33];
    __shared__ float red[256];
    const int t = threadIdx.x, lane = t & 63, wv = t >> 6;
    const int ml = lane & 15, kg = lane >> 4;
    const int b0 = blockIdx.x * 16;
    f32x4 acc = {};
    for (int kt = 0; kt < 16; ++kt){
        s16x8 b = *(const s16x8*)&Bp[(wv * 16 + kt) * 512 + lane * 8];
        s16x8 a = *(const s16x8*)&Hbf[(size_t)(b0 + ml) * 512 + kt * 32 + kg * 8];
        acc = __builtin_amdgcn_mfma_f32_16x16x32_bf16(a, b, acc, 0, 0, 0);
    }
    {
        int col = wv * 16 + ml;
        float bv = b2[col];
        #pragma unroll
        for (int r = 0; r < 4; ++r)
            P[kg * 4 + r][col] = acc[r] + bv;
    }
    __syncthreads();
    float klp = 0.f;
    #pragma unroll
    for (int q = 0; q < 2; ++q){
        int e = q * 256 + t;
        int row = e >> 5, n = e & 31;
        float mean = P[row][n], ls = P[row][n + 32];
        float sd = expf(ls);
        size_t o = (size_t)(b0 + row) * 32 + n;
        float z = fmaf(sd, eps[o], mean);
        omean[o] = mean; ostd[o] = sd;
        zs[row][n] = z;
        klp += mean * mean + sd * sd - 2.f * ls - 1.f;
    }
    __syncthreads();
    #pragma unroll
    for (int q = 0; q < 2; ++q){
        int e = q * 256 + t;
        int n = e >> 4, row = e & 15;
        zt[(size_t)n * 4096 + b0 + row] = zs[row][n];
    }
    red[t] = klp; __syncthreads();
    for (int s = 128; s > 0; s >>= 1){ if (t < s) red[t] += red[t + s]; __syncthreads(); }
    if (t == 0) atomicAdd(accg + 0, red[0]);
}

// ---------------------------------------------------------------------------
// K_mi: MI pair-MLPs. grid = 496 p x 4 chunks of 1024 rows; wave = 16 tiles.
// Rolled loop (low VGPR) + explicit one-ahead z prefetch (hides L2 latency
// across the tile's compute) + persistent f32x4 C-init vectors (no per-tile
// bias movs). NO unroll pragma on the tile loop (R4/R6 lesson).
// ---------------------------------------------------------------------------
__global__ __launch_bounds__(256) void k_mi(
    const float* __restrict__ zt,
    const float* __restrict__ w1g, const float* __restrict__ b1g,
    const short* __restrict__ w2p, const float* __restrict__ b2g,
    const float* __restrict__ w3g, float* __restrict__ macc)
{
    const int lane = threadIdx.x & 63, wv = threadIdx.x >> 6;
    const int ml = lane & 15, kg = lane >> 4;
    const int p = blockIdx.x >> 2, bq = blockIdx.x & 3;
    int pi = 0, rem = p;
    while (rem >= 31 - pi){ rem -= 31 - pi; ++pi; }
    const int pj = pi + 1 + rem;

    const int zrow = wv * 16 + ml;
    const float* zi_b = zt + (size_t)pi * 4096 + bq * 1024 + zrow;
    const float* zj_b = zt + (size_t)pj * 4096 + bq * 1024 + zrow;

    float w10s[2][8], w11s[2][8], b1s[2][8];
    #pragma unroll
    for (int ks = 0; ks < 2; ++ks)
        #pragma unroll
        for (int i2 = 0; i2 < 8; ++i2){
            int h = ks * 32 + kg * 8 + i2;
            w10s[ks][i2] = 0.6f * w1g[p * 128 + h];
            w11s[ks][i2] = 0.6f * w1g[p * 128 + 64 + h];
            b1s[ks][i2]  = 0.6f * b1g[p * 64 + h];
        }
    s16x8 bfr[4][2];
    f32x4 b2c[4];
    #pragma unroll
    for (int nb = 0; nb < 4; ++nb){
        float bv = b2g[p * 64 + nb * 16 + ml];
        b2c[nb][0] = bv; b2c[nb][1] = bv; b2c[nb][2] = bv; b2c[nb][3] = bv;
        #pragma unroll
        for (int ks = 0; ks < 2; ++ks)
            bfr[nb][ks] = *(const s16x8*)&w2p[(size_t)p * 4096 + (nb * 2 + ks) * 512 + lane * 8];
    }
    float slin[4] = {0.f, 0.f, 0.f, 0.f}, sabs[4] = {0.f, 0.f, 0.f, 0.f};
    float zi_c = zi_b[0], zj_c = zj_b[0];
    #pragma unroll 1
    for (int tile = 0; tile < 16; ++tile){
        int nx = (tile < 15 ? tile + 1 : 15) * 64;
        float zi_n = zi_b[nx], zj_n = zj_b[nx];
        s16x8 af0, af1;
        #pragma unroll
        for (int i2 = 0; i2 < 8; ++i2){
            float m0 = fmaf(zi_c, w10s[0][i2], fmaf(zj_c, w11s[0][i2], b1s[0][i2]));
            m0 = fmaf(0.66666669f, fabsf(m0), m0);
            af0[i2] = f2bf(m0);
            float m1 = fmaf(zi_c, w10s[1][i2], fmaf(zj_c, w11s[1][i2], b1s[1][i2]));
            m1 = fmaf(0.66666669f, fabsf(m1), m1);
            af1[i2] = f2bf(m1);
        }
        #pragma unroll
        for (int nb = 0; nb < 4; ++nb){
            f32x4 d = __builtin_amdgcn_mfma_f32_16x16x32_bf16(af0, bfr[nb][0], b2c[nb], 0, 0, 0);
            d = __builtin_amdgcn_mfma_f32_16x16x32_bf16(af1, bfr[nb][1], d, 0, 0, 0);
            #pragma unroll
            for (int r2 = 0; r2 < 4; ++r2){
                slin[nb] += d[r2];
                sabs[nb] += fabsf(d[r2]);
            }
        }
        zi_c = zi_n; zj_c = zj_n;
    }
    float s = 0.f;
    #pragma unroll
    for (int nb = 0; nb < 4; ++nb){
        float w3 = w3g[p * 64 + nb * 16 + ml];
        s = fmaf(0.6f * w3, slin[nb], fmaf(0.4f * w3, sabs[nb], s));
    }
    #pragma unroll
    for (int off = 32; off; off >>= 1) s += __shfl_xor(s, off);
    if (lane == 0) atomicAdd(&macc[p], s);
}

// ---------------------------------------------------------------------------
// K_mech: per-i mech MLP via MFMA. grid (64 row-blocks, 32 i).
// ---------------------------------------------------------------------------
__global__ __launch_bounds__(256) void k_mech(
    const float* __restrict__ zt, const float* __restrict__ A,
    const short* __restrict__ W1p, const float* __restrict__ mb1,
    const float* __restrict__ mw2, const float* __restrict__ mb2,
    float* __restrict__ out_zc)
{
    __shared__ float sA[32], sB1[256], sW2[256];
    const int t = threadIdx.x, lane = t & 63, wv = t >> 6;
    const int ml = lane & 15, kg = lane >> 4;
    const int i = blockIdx.y;
    const int b0 = blockIdx.x * 64 + wv * 16;
    if (t < 32) sA[t] = A[t * 32 + i];
    sB1[t] = mb1[i * 256 + t];
    sW2[t] = mw2[i * 256 + t];
    __syncthreads();
    float zv[8];
    #pragma unroll
    for (int q = 0; q < 8; ++q)
        zv[q] = zt[(size_t)(kg * 8 + q) * 4096 + b0 + ml];
    s16x8 af;
    #pragma unroll
    for (int q = 0; q < 8; ++q)
        af[q] = f2bf(zv[q] * sA[kg * 8 + q]);
    float s[4] = {0.f, 0.f, 0.f, 0.f};
    #pragma unroll
    for (int nt = 0; nt < 16; ++nt){
        s16x8 bf = *(const s16x8*)&W1p[i * 8192 + nt * 512 + lane * 8];
        int col = nt * 16 + ml;
        float b1v = sB1[col], w2v = sW2[col];
        f32x4 d;
        d[0] = b1v; d[1] = b1v; d[2] = b1v; d[3] = b1v;
        d = __builtin_amdgcn_mfma_f32_16x16x32_bf16(af, bf, d, 0, 0, 0);
        float w2a = 0.6f * w2v, w2b = 0.4f * w2v;
        #pragma unroll
        for (int r = 0; r < 4; ++r)
            s[r] = fmaf(w2a, d[r], fmaf(w2b, fabsf(d[r]), s[r]));
    }
    #pragma unroll
    for (int off = 1; off < 16; off <<= 1)
        #pragma unroll
        for (int r = 0; r < 4; ++r) s[r] += __shfl_xor(s[r], off);
    if (ml == 0){
        float bb = mb2[i];
        #pragma unroll
        for (int r = 0; r < 4; ++r){
            int b = b0 + kg * 4 + r;
            out_zc[(size_t)b * 32 + i] = s[r] + bb;
        }
    }
}

// ---------------------------------------------------------------------------
// K5: d1 = leaky(z_causal @ dec_w1 + dec_b1), bf16 out (reads zc from d_out).
// ---------------------------------------------------------------------------
__global__ __launch_bounds__(256) void k_dec1(
    const float* __restrict__ zc, const float* __restrict__ w1,
    const float* __restrict__ b1, short* __restrict__ d1)
{
    int gid = blockIdx.x * 256 + threadIdx.x;
    int b = gid >> 9, hc = gid & 511;
    const f32x4* z4 = (const f32x4*)(zc + (size_t)b * 32);
    float a = b1[hc];
    #pragma unroll
    for (int q = 0; q < 8; ++q){
        f32x4 v = z4[q];
        a = fmaf(v[0], w1[(q * 4 + 0) * 512 + hc], a);
        a = fmaf(v[1], w1[(q * 4 + 1) * 512 + hc], a);
        a = fmaf(v[2], w1[(q * 4 + 2) * 512 + hc], a);
        a = fmaf(v[3], w1[(q * 4 + 3) * 512 + hc], a);
    }
    d1[(size_t)b * 512 + hc] = f2bf(leaky2(a));
}

// ---------------------------------------------------------------------------
// K8: finalize all scalar losses
// ---------------------------------------------------------------------------
__global__ void k_final(const float* __restrict__ acc, const float* __restrict__ lw,
                        const float* __restrict__ b3, float* __restrict__ outs)
{
    __shared__ float red[512];
    int t = threadIdx.x;
    float c = 0.f;
    if (t < 496){
        int pi = 0, rem = t;
        while (rem >= 31 - pi){ rem -= 31 - pi; ++pi; }
        int pj = pi + 1 + rem;
        float est = acc[4 + t] * (1.f / 4096.f) + b3[t];
        float w = 1.f / (1.f + expf(-lw[pi * 32 + pj]));
        c = w * est;
    }
    red[t] = c; __syncthreads();
    for (int s = 256; s > 0; s >>= 1){ if (t < s) red[t] += red[t + s]; __syncthreads(); }
    if (t == 0){
        float mi    = red[0];
        float recon = acc[1] * (1.f / (4096.f * 512.f));
        float kl    = 0.5f * acc[0] * (1.f / 4096.f);
        float sp    = acc[2], dag = acc[3];
        outs[0] = recon + kl + 0.1f * sp + 0.01f * mi + dag;
        outs[1] = recon; outs[2] = kl; outs[3] = sp; outs[4] = mi; outs[5] = dag;
    }
}

// ---------------------------------------------------------------------------
extern "C" void kernel_launch(void* const* d_in, const int* in_sizes, int n_in,
                              void* d_out, int out_size, void* d_ws, size_t ws_size,
                              hipStream_t stream)
{
    const float* features = (const float*)d_in[0];
    const float* eps      = (const float*)d_in[1];
    const float* enc_w1   = (const float*)d_in[2];
    const float* enc_b1   = (const float*)d_in[3];
    const float* enc_w2   = (const float*)d_in[4];
    const float* enc_b2   = (const float*)d_in[5];
    const float* log_w    = (const float*)d_in[6];
    const float* mech_w1  = (const float*)d_in[7];
    const float* mech_b1  = (const float*)d_in[8];
    const float* mech_w2  = (const float*)d_in[9];
    const float* mech_b2  = (const float*)d_in[10];
    const float* dec_w1   = (const float*)d_in[11];
    const float* dec_b1   = (const float*)d_in[12];
    const float* dec_w2   = (const float*)d_in[13];
    const float* dec_b2   = (const float*)d_in[14];
    const float* mi_w1    = (const float*)d_in[15];
    const float* mi_b1    = (const float*)d_in[16];
    const float* mi_w2    = (const float*)d_in[17];
    const float* mi_b2    = (const float*)d_in[18];
    const float* mi_w3    = (const float*)d_in[19];
    const float* mi_b3    = (const float*)d_in[20];

    float* W      = (float*)d_ws;
    float* zt     = W;                         // 131072 f32 (z transposed [32][4096])
    float* Abuf   = W + 262144;                // 1024
    float* accums = W + 263168;                // 512
    short* w1p    = (short*)(W + 263680);      // 262144 bf16
    short* ew2p   = (short*)(W + 394752);      // 32768 bf16
    short* dw2p   = (short*)(W + 411136);      // 262144 bf16
    short* mw1p   = (short*)(W + 542208);      // 262144 bf16
    short* d1bf   = (short*)(W + 673280);      // 2097152 bf16
    short* mw2p   = d1bf;                      // alias: dead before k_dec1 writes
    float* out    = (float*)d_out;
    short* featbf = (short*)(out + 393216);            // scratch in dead recon region
    short* hbf    = (short*)(out + 393216 + 1048576);

    hipMemsetAsync(accums, 0, 512 * sizeof(float), stream);
    k_cvt<<<2049, 256, 0, stream>>>(features, enc_w1, enc_w2, dec_w2, mech_w1, mi_w2,
                                    featbf, w1p, ew2p, dw2p, mw1p, mw2p,
                                    log_w, Abuf, accums);
    k_genc<<<dim3(128, 4), 256, 0, stream>>>(featbf, w1p, enc_b1, hbf);
    k_pmfma<<<256, 256, 0, stream>>>(hbf, ew2p, enc_b2, eps,
                                     out + 131072, out + 262144, zt, accums);
    k_mi<<<1984, 256, 0, stream>>>(zt, mi_w1, mi_b1, mw2p, mi_b2, mi_w3, accums + 4);
    k_mech<<<dim3(64, 32), 256, 0, stream>>>(zt, Abuf, mw1p, mech_b1, mech_w2, mech_b2, out);
    k_dec1<<<8192, 256, 0, stream>>>(out, dec_w1, dec_b1, d1bf);
    k_grec<<<dim3(128, 4), 256, 0, stream>>>(d1bf, dw2p, dec_b2, features,
                                             out + 393216, accums);
    k_final<<<1, 512, 0, stream>>>(accums, log_w, mi_b3, out + 2490368);
}

// Round 9
// 129.455 us; speedup vs baseline: 1.0307x; 1.0307x over previous
//
#include <hip/hip_runtime.h>
#include <hip/hip_bf16.h>

typedef float f32x4 __attribute__((ext_vector_type(4)));
typedef float f32x2 __attribute__((ext_vector_type(2)));
typedef short s16x8 __attribute__((ext_vector_type(8)));

__device__ __forceinline__ float leaky2(float x){ return fmaf(0.4f, fabsf(x), 0.6f * x); }

__device__ __forceinline__ short f2bf(float f){
    return __builtin_bit_cast(short, __float2bfloat16(f));
}

// ---------------------------------------------------------------------------
// K_cvt: bf16 copies + packed MFMA B-fragment layouts, reads coalesced.
// Block 2048 runs setup math (A, sparsity, DAG). Adds dec_w1 packing (dw1p).
// ---------------------------------------------------------------------------
__global__ __launch_bounds__(256) void k_cvt(
    const float* __restrict__ feat, const float* __restrict__ ew1,
    const float* __restrict__ ew2, const float* __restrict__ dw2,
    const float* __restrict__ mw1, const float* __restrict__ mw2,
    const float* __restrict__ dw1,
    short* __restrict__ featbf, short* __restrict__ w1p,
    short* __restrict__ ew2p, short* __restrict__ dw2p,
    short* __restrict__ mw1p, short* __restrict__ mw2p,
    short* __restrict__ dw1p,
    const float* __restrict__ lw, float* __restrict__ A,
    float* __restrict__ acc)
{
    if (blockIdx.x >= 2048){
        __shared__ float A2s[1024], mp[1024], red[256];
        const int t = threadIdx.x;
        float part = 0.f;
        #pragma unroll
        for (int q = 0; q < 4; ++q){
            int e = t * 4 + q;
            int r = e >> 5, c = e & 31;
            float v = lw[e];
            float sig = 1.f / (1.f + expf(-v));
            float l2 = (r < c) ? v * 10.f : ((r == c) ? -100.f : 0.f);
            A[e] = 1.f / (1.f + expf(-l2));
            part += sig;
            float a2 = sig * sig;
            A2s[e] = a2; mp[e] = a2;
        }
        red[t] = part; __syncthreads();
        for (int s = 128; s > 0; s >>= 1){ if (t < s) red[t] += red[t + s]; __syncthreads(); }
        if (t == 0) acc[2] = red[0];

        const float invf[10] = {0.f, 1.f, 0.5f, 1.6666667e-1f, 4.1666667e-2f,
                                8.3333333e-3f, 1.3888889e-3f, 1.9841270e-4f,
                                2.4801587e-5f, 2.7557319e-6f};
        float tr = 0.f;
        const int r = t >> 3, c0 = (t & 7) * 4;
        for (int n = 1; n <= 9; ++n){
            __syncthreads();
            if (t == 0){
                float s = 0.f;
                for (int k2 = 0; k2 < 32; ++k2) s += mp[k2 * 33];
                tr += s * invf[n];
            }
            if (n == 9) break;
            float av[4] = {0.f, 0.f, 0.f, 0.f};
            for (int k2 = 0; k2 < 32; ++k2){
                float m = mp[r * 32 + k2];
                #pragma unroll
                for (int q = 0; q < 4; ++q) av[q] = fmaf(m, A2s[k2 * 32 + c0 + q], av[q]);
            }
            __syncthreads();
            #pragma unroll
            for (int q = 0; q < 4; ++q) mp[r * 32 + c0 + q] = av[q];
        }
        if (t == 0) acc[3] = tr * tr;
        return;
    }
    for (int idx = blockIdx.x * 256 + threadIdx.x; idx < 4964352; idx += 2048 * 256){
        if (idx < 2097152){ featbf[idx] = f2bf(feat[idx]); continue; }
        int s = idx - 2097152;
        if (s < 262144){                     // enc_w1 [512][512]
            int k = s >> 9, n = s & 511;
            int lane = (((k >> 3) & 3) << 4) | (n & 15);
            w1p[((n >> 4) * 16 + (k >> 5)) * 512 + lane * 8 + (k & 7)] = f2bf(ew1[s]);
            continue;
        }
        s -= 262144;
        if (s < 32768){                      // enc_w2 [512][64]
            int k = s >> 6, n = s & 63;
            int lane = (((k >> 3) & 3) << 4) | (n & 15);
            ew2p[((n >> 4) * 16 + (k >> 5)) * 512 + lane * 8 + (k & 7)] = f2bf(ew2[s]);
            continue;
        }
        s -= 32768;
        if (s < 262144){                     // dec_w2 [512][512]
            int k = s >> 9, n = s & 511;
            int lane = (((k >> 3) & 3) << 4) | (n & 15);
            dw2p[((n >> 4) * 16 + (k >> 5)) * 512 + lane * 8 + (k & 7)] = f2bf(dw2[s]);
            continue;
        }
        s -= 262144;
        if (s < 262144){                     // mech_w1 [32][32][256]
            int i = s >> 13, r2 = s & 8191;
            int k = r2 >> 8, n = r2 & 255;
            int lane = (((k >> 3) & 3) << 4) | (n & 15);
            mw1p[i * 8192 + (n >> 4) * 512 + lane * 8 + (k & 7)] = f2bf(mw1[s]);
            continue;
        }
        s -= 262144;
        if (s < 2031616){                    // mi_w2 [496][64][64]
            int p = s >> 12, r2 = s & 4095;
            int k = r2 >> 6, n = r2 & 63;
            int lane = (((k >> 3) & 3) << 4) | (n & 15);
            mw2p[p * 4096 + ((n >> 4) * 2 + (k >> 5)) * 512 + lane * 8 + (k & 7)] = f2bf(mw2[s]);
            continue;
        }
        s -= 2031616;                        // dec_w1 [32][512]
        int k = s >> 9, n = s & 511;
        int lane = (((k >> 3) & 3) << 4) | (n & 15);
        dw1p[(n >> 4) * 512 + lane * 8 + (k & 7)] = f2bf(dw1[s]);
    }
}

// ---------------------------------------------------------------------------
// K_encf: fused encoder. Phase 1: h = leaky(feat@enc_w1+b1) -> swizzled LDS.
// Phase 2: params = h@enc_w2+b2 -> mean/std/z/KL, zt transposed out.
// 256 blocks x 16 rows.
// ---------------------------------------------------------------------------
__global__ __launch_bounds__(256) void k_encf(
    const short* __restrict__ featbf, const short* __restrict__ w1p,
    const float* __restrict__ eb1, const short* __restrict__ ew2p,
    const float* __restrict__ eb2, const float* __restrict__ eps,
    float* __restrict__ omean, float* __restrict__ ostd,
    float* __restrict__ zt, float* __restrict__ accg)
{
    __shared__ short hlds[8192];           // 16 x 512 bf16, XOR-swizzled
    __shared__ float P[16][65];
    __shared__ float zs[16][33];
    __shared__ float red[256];
    const int t = threadIdx.x, lane = t & 63, wv = t >> 6;
    const int ml = lane & 15, kg = lane >> 4;
    const int b0 = blockIdx.x * 16;

    // ---- phase 1: 16 x 512 GEMM, wave wv covers cols wv*128..wv*128+128
    f32x4 acc1[8] = {};
    for (int kt = 0; kt < 16; ++kt){
        s16x8 a = *(const s16x8*)&featbf[(size_t)(b0 + ml) * 512 + kt * 32 + kg * 8];
        #pragma unroll
        for (int nf = 0; nf < 8; ++nf){
            s16x8 b = *(const s16x8*)&w1p[((wv * 8 + nf) * 16 + kt) * 512 + lane * 8];
            acc1[nf] = __builtin_amdgcn_mfma_f32_16x16x32_bf16(a, b, acc1[nf], 0, 0, 0);
        }
    }
    #pragma unroll
    for (int nf = 0; nf < 8; ++nf){
        int col = wv * 128 + nf * 16 + ml;
        float bv = eb1[col];
        #pragma unroll
        for (int r = 0; r < 4; ++r){
            int row = kg * 4 + r;
            int byte = (row * 1024 + col * 2) ^ ((row & 7) << 4);
            hlds[byte >> 1] = f2bf(leaky2(acc1[nf][r] + bv));
        }
    }
    __syncthreads();

    // ---- phase 2: params = h @ enc_w2 (K=512, N=64; wave wv owns n-frag wv)
    f32x4 acc2 = {};
    for (int kt = 0; kt < 16; ++kt){
        int byte = (ml * 1024 + kt * 64 + kg * 16) ^ ((ml & 7) << 4);
        s16x8 a = *(const s16x8*)((const char*)hlds + byte);
        s16x8 b = *(const s16x8*)&ew2p[(wv * 16 + kt) * 512 + lane * 8];
        acc2 = __builtin_amdgcn_mfma_f32_16x16x32_bf16(a, b, acc2, 0, 0, 0);
    }
    {
        int col = wv * 16 + ml;
        float bv = eb2[col];
        #pragma unroll
        for (int r = 0; r < 4; ++r)
            P[kg * 4 + r][col] = acc2[r] + bv;
    }
    __syncthreads();
    float klp = 0.f;
    #pragma unroll
    for (int q = 0; q < 2; ++q){
        int e = q * 256 + t;
        int row = e >> 5, n = e & 31;
        float mean = P[row][n], ls = P[row][n + 32];
        float sd = expf(ls);
        size_t o = (size_t)(b0 + row) * 32 + n;
        float z = fmaf(sd, eps[o], mean);
        omean[o] = mean; ostd[o] = sd;
        zs[row][n] = z;
        klp += mean * mean + sd * sd - 2.f * ls - 1.f;
    }
    __syncthreads();
    #pragma unroll
    for (int q = 0; q < 2; ++q){
        int e = q * 256 + t;
        int n = e >> 4, row = e & 15;
        zt[(size_t)n * 4096 + b0 + row] = zs[row][n];
    }
    red[t] = klp; __syncthreads();
    for (int s = 128; s > 0; s >>= 1){ if (t < s) red[t] += red[t + s]; __syncthreads(); }
    if (t == 0) atomicAdd(accg + 0, red[0]);
}

// ---------------------------------------------------------------------------
// K_mimech: MI pair-MLPs (blocks 0..1983) + mech MLPs (1984..4031).
// MI branch: R8's 80-VGPR shape, layer-1 on f32x2 (v_pk_fma candidate).
// ---------------------------------------------------------------------------
__global__ __launch_bounds__(256) void k_mimech(
    const float* __restrict__ zt,
    const float* __restrict__ w1g, const float* __restrict__ b1g,
    const short* __restrict__ w2p, const float* __restrict__ b2g,
    const float* __restrict__ w3g, float* __restrict__ macc,
    const float* __restrict__ A, const short* __restrict__ W1p,
    const float* __restrict__ mb1, const float* __restrict__ mw2,
    const float* __restrict__ mb2, float* __restrict__ out_zc)
{
    __shared__ float sA[32], sB1[256], sW2[256];
    const int t = threadIdx.x, lane = t & 63, wv = t >> 6;
    const int ml = lane & 15, kg = lane >> 4;
    if (blockIdx.x < 1984){
        // ---------------- MI ----------------
        const int p = blockIdx.x >> 2, bq = blockIdx.x & 3;
        int pi = 0, rem = p;
        while (rem >= 31 - pi){ rem -= 31 - pi; ++pi; }
        const int pj = pi + 1 + rem;

        const int zrow = wv * 16 + ml;
        const float* zi_b = zt + (size_t)pi * 4096 + bq * 1024 + zrow;
        const float* zj_b = zt + (size_t)pj * 4096 + bq * 1024 + zrow;

        f32x2 w10v[2][4], w11v[2][4], b1v[2][4];
        #pragma unroll
        for (int ks = 0; ks < 2; ++ks)
            #pragma unroll
            for (int q = 0; q < 4; ++q){
                int h = ks * 32 + kg * 8 + q * 2;
                w10v[ks][q] = *(const f32x2*)&w1g[p * 128 + h] * 0.6f;
                w11v[ks][q] = *(const f32x2*)&w1g[p * 128 + 64 + h] * 0.6f;
                b1v[ks][q]  = *(const f32x2*)&b1g[p * 64 + h] * 0.6f;
            }
        s16x8 bfr[4][2];
        f32x4 b2c[4];
        #pragma unroll
        for (int nb = 0; nb < 4; ++nb){
            float bv = b2g[p * 64 + nb * 16 + ml];
            b2c[nb][0] = bv; b2c[nb][1] = bv; b2c[nb][2] = bv; b2c[nb][3] = bv;
            #pragma unroll
            for (int ks = 0; ks < 2; ++ks)
                bfr[nb][ks] = *(const s16x8*)&w2p[(size_t)p * 4096 + (nb * 2 + ks) * 512 + lane * 8];
        }
        const f32x2 c23 = {0.66666669f, 0.66666669f};
        float slin[4] = {0.f, 0.f, 0.f, 0.f}, sabs[4] = {0.f, 0.f, 0.f, 0.f};
        #pragma unroll 1
        for (int tile = 0; tile < 16; ++tile){
            float zi_c = zi_b[tile * 64], zj_c = zj_b[tile * 64];
            f32x2 zi2 = {zi_c, zi_c}, zj2 = {zj_c, zj_c};
            s16x8 af0, af1;
            #pragma unroll
            for (int q = 0; q < 4; ++q){
                f32x2 m0 = __builtin_elementwise_fma(zi2, w10v[0][q],
                           __builtin_elementwise_fma(zj2, w11v[0][q], b1v[0][q]));
                m0 = __builtin_elementwise_fma(c23, __builtin_elementwise_abs(m0), m0);
                af0[q * 2] = f2bf(m0[0]); af0[q * 2 + 1] = f2bf(m0[1]);
                f32x2 m1 = __builtin_elementwise_fma(zi2, w10v[1][q],
                           __builtin_elementwise_fma(zj2, w11v[1][q], b1v[1][q]));
                m1 = __builtin_elementwise_fma(c23, __builtin_elementwise_abs(m1), m1);
                af1[q * 2] = f2bf(m1[0]); af1[q * 2 + 1] = f2bf(m1[1]);
            }
            #pragma unroll
            for (int nb = 0; nb < 4; ++nb){
                f32x4 d = __builtin_amdgcn_mfma_f32_16x16x32_bf16(af0, bfr[nb][0], b2c[nb], 0, 0, 0);
                d = __builtin_amdgcn_mfma_f32_16x16x32_bf16(af1, bfr[nb][1], d, 0, 0, 0);
                #pragma unroll
                for (int r2 = 0; r2 < 4; ++r2){
                    slin[nb] += d[r2];
                    sabs[nb] += fabsf(d[r2]);
                }
            }
        }
        float s = 0.f;
        #pragma unroll
        for (int nb = 0; nb < 4; ++nb){
            float w3 = w3g[p * 64 + nb * 16 + ml];
            s = fmaf(0.6f * w3, slin[nb], fmaf(0.4f * w3, sabs[nb], s));
        }
        #pragma unroll
        for (int off = 32; off; off >>= 1) s += __shfl_xor(s, off);
        if (lane == 0) atomicAdd(&macc[p], s);
    } else {
        // ---------------- mech ----------------
        const int bx = blockIdx.x - 1984;
        const int i = bx & 31;
        const int b0 = (bx >> 5) * 64 + wv * 16;
        if (t < 32) sA[t] = A[t * 32 + i];
        sB1[t] = mb1[i * 256 + t];
        sW2[t] = mw2[i * 256 + t];
        __syncthreads();
        float zv[8];
        #pragma unroll
        for (int q = 0; q < 8; ++q)
            zv[q] = zt[(size_t)(kg * 8 + q) * 4096 + b0 + ml];
        s16x8 af;
        #pragma unroll
        for (int q = 0; q < 8; ++q)
            af[q] = f2bf(zv[q] * sA[kg * 8 + q]);
        float s[4] = {0.f, 0.f, 0.f, 0.f};
        #pragma unroll
        for (int nt = 0; nt < 16; ++nt){
            s16x8 bf = *(const s16x8*)&W1p[i * 8192 + nt * 512 + lane * 8];
            int col = nt * 16 + ml;
            float b1e = sB1[col], w2v = sW2[col];
            f32x4 d;
            d[0] = b1e; d[1] = b1e; d[2] = b1e; d[3] = b1e;
            d = __builtin_amdgcn_mfma_f32_16x16x32_bf16(af, bf, d, 0, 0, 0);
            float w2a = 0.6f * w2v, w2b = 0.4f * w2v;
            #pragma unroll
            for (int r = 0; r < 4; ++r)
                s[r] = fmaf(w2a, d[r], fmaf(w2b, fabsf(d[r]), s[r]));
        }
        #pragma unroll
        for (int off = 1; off < 16; off <<= 1)
            #pragma unroll
            for (int r = 0; r < 4; ++r) s[r] += __shfl_xor(s[r], off);
        if (ml == 0){
            float bb = mb2[i];
            #pragma unroll
            for (int r = 0; r < 4; ++r){
                int b = b0 + kg * 4 + r;
                out_zc[(size_t)b * 32 + i] = s[r] + bb;
            }
        }
    }
}

// ---------------------------------------------------------------------------
// K_decf: fused decoder. Phase 1: d1 = leaky(zc@dec_w1+b1) -> swizzled LDS
// (32x512, computed redundantly per col-group). Phase 2: recon = d1@dec_w2+b2
// + recon-loss. grid (128 row-blocks, 4 col-groups).
// ---------------------------------------------------------------------------
__global__ __launch_bounds__(256) void k_decf(
    const float* __restrict__ zc, const short* __restrict__ dw1p,
    const float* __restrict__ db1, const short* __restrict__ dw2p,
    const float* __restrict__ db2, const float* __restrict__ feat,
    float* __restrict__ recon, float* __restrict__ accg)
{
    __shared__ short dlds[16384];          // 32 x 512 bf16, XOR-swizzled
    __shared__ float red[256];
    const int t = threadIdx.x, lane = t & 63, wv = t >> 6;
    const int ml = lane & 15, kg = lane >> 4;
    const int b0 = blockIdx.x * 32;
    const int c0 = blockIdx.y * 128;

    // ---- phase 1: d1[32][512] from zc (K=32), wave wv covers cols wv*128..
    s16x8 af[2];
    #pragma unroll
    for (int m = 0; m < 2; ++m){
        int row = b0 + m * 16 + ml;
        f32x4 z0 = *(const f32x4*)&zc[(size_t)row * 32 + kg * 8];
        f32x4 z1 = *(const f32x4*)&zc[(size_t)row * 32 + kg * 8 + 4];
        #pragma unroll
        for (int e = 0; e < 4; ++e){
            af[m][e] = f2bf(z0[e]);
            af[m][e + 4] = f2bf(z1[e]);
        }
    }
    #pragma unroll
    for (int nf = 0; nf < 8; ++nf){
        int nt = wv * 8 + nf;
        s16x8 bf = *(const s16x8*)&dw1p[nt * 512 + lane * 8];
        int col = nt * 16 + ml;
        float b1e = db1[col];
        f32x4 c; c[0] = b1e; c[1] = b1e; c[2] = b1e; c[3] = b1e;
        #pragma unroll
        for (int m = 0; m < 2; ++m){
            f32x4 d = __builtin_amdgcn_mfma_f32_16x16x32_bf16(af[m], bf, c, 0, 0, 0);
            #pragma unroll
            for (int r = 0; r < 4; ++r){
                int row = m * 16 + kg * 4 + r;
                int byte = (row * 1024 + col * 2) ^ ((row & 7) << 4);
                dlds[byte >> 1] = f2bf(leaky2(d[r]));
            }
        }
    }
    __syncthreads();

    // ---- phase 2: recon tile 32 x 128 (wave wv: 2 n-frags), K=512
    f32x4 acc[2][2] = {};
    for (int kt = 0; kt < 16; ++kt){
        s16x8 a[2];
        #pragma unroll
        for (int m = 0; m < 2; ++m){
            int row = m * 16 + ml;
            int byte = (row * 1024 + kt * 64 + kg * 16) ^ ((row & 7) << 4);
            a[m] = *(const s16x8*)((const char*)dlds + byte);
        }
        #pragma unroll
        for (int j = 0; j < 2; ++j){
            int nt = (c0 >> 4) + wv * 2 + j;
            s16x8 b = *(const s16x8*)&dw2p[(nt * 16 + kt) * 512 + lane * 8];
            #pragma unroll
            for (int m = 0; m < 2; ++m)
                acc[m][j] = __builtin_amdgcn_mfma_f32_16x16x32_bf16(a[m], b, acc[m][j], 0, 0, 0);
        }
    }
    float lsum = 0.f;
    #pragma unroll
    for (int j = 0; j < 2; ++j){
        int col = c0 + (wv * 2 + j) * 16 + ml;
        float bv = db2[col];
        #pragma unroll
        for (int m = 0; m < 2; ++m)
            #pragma unroll
            for (int r = 0; r < 4; ++r){
                int row = b0 + m * 16 + kg * 4 + r;
                float v = acc[m][j][r] + bv;
                float d = v - feat[(size_t)row * 512 + col];
                lsum = fmaf(d, d, lsum);
                recon[(size_t)row * 512 + col] = v;
            }
    }
    red[t] = lsum; __syncthreads();
    for (int s = 128; s > 0; s >>= 1){ if (t < s) red[t] += red[t + s]; __syncthreads(); }
    if (t == 0) atomicAdd(accg + 1, red[0]);
}

// ---------------------------------------------------------------------------
// K_final: finalize all scalar losses
// ---------------------------------------------------------------------------
__global__ void k_final(const float* __restrict__ acc, const float* __restrict__ lw,
                        const float* __restrict__ b3, float* __restrict__ outs)
{
    __shared__ float red[512];
    int t = threadIdx.x;
    float c = 0.f;
    if (t < 496){
        int pi = 0, rem = t;
        while (rem >= 31 - pi){ rem -= 31 - pi; ++pi; }
        int pj = pi + 1 + rem;
        float est = acc[4 + t] * (1.f / 4096.f) + b3[t];
        float w = 1.f / (1.f + expf(-lw[pi * 32 + pj]));
        c = w * est;
    }
    red[t] = c; __syncthreads();
    for (int s = 256; s > 0; s >>= 1){ if (t < s) red[t] += red[t + s]; __syncthreads(); }
    if (t == 0){
        float mi    = red[0];
        float recon = acc[1] * (1.f / (4096.f * 512.f));
        float kl    = 0.5f * acc[0] * (1.f / 4096.f);
        float sp    = acc[2], dag = acc[3];
        outs[0] = recon + kl + 0.1f * sp + 0.01f * mi + dag;
        outs[1] = recon; outs[2] = kl; outs[3] = sp; outs[4] = mi; outs[5] = dag;
    }
}

// ---------------------------------------------------------------------------
extern "C" void kernel_launch(void* const* d_in, const int* in_sizes, int n_in,
                              void* d_out, int out_size, void* d_ws, size_t ws_size,
                              hipStream_t stream)
{
    const float* features = (const float*)d_in[0];
    const float* eps      = (const float*)d_in[1];
    const float* enc_w1   = (const float*)d_in[2];
    const float* enc_b1   = (const float*)d_in[3];
    const float* enc_w2   = (const float*)d_in[4];
    const float* enc_b2   = (const float*)d_in[5];
    const float* log_w    = (const float*)d_in[6];
    const float* mech_w1  = (const float*)d_in[7];
    const float* mech_b1  = (const float*)d_in[8];
    const float* mech_w2  = (const float*)d_in[9];
    const float* mech_b2  = (const float*)d_in[10];
    const float* dec_w1   = (const float*)d_in[11];
    const float* dec_b1   = (const float*)d_in[12];
    const float* dec_w2   = (const float*)d_in[13];
    const float* dec_b2   = (const float*)d_in[14];
    const float* mi_w1    = (const float*)d_in[15];
    const float* mi_b1    = (const float*)d_in[16];
    const float* mi_w2    = (const float*)d_in[17];
    const float* mi_b2    = (const float*)d_in[18];
    const float* mi_w3    = (const float*)d_in[19];
    const float* mi_b3    = (const float*)d_in[20];

    float* W      = (float*)d_ws;
    float* zt     = W;                         // [32][4096] f32
    float* Abuf   = W + 262144;                // 1024
    float* accums = W + 263168;                // 512
    short* w1p    = (short*)(W + 263680);      // 262144 sh
    short* ew2p   = (short*)(W + 394752);      // 32768 sh
    short* dw2p   = (short*)(W + 411136);      // 262144 sh
    short* mw1p   = (short*)(W + 542208);      // 262144 sh
    short* mw2p   = (short*)(W + 673280);      // 2031616 sh
    short* dw1p   = (short*)(W + 1689088);     // 16384 sh
    float* out    = (float*)d_out;
    short* featbf = (short*)(out + 393216);    // scratch in dead recon region

    hipMemsetAsync(accums, 0, 512 * sizeof(float), stream);
    k_cvt<<<2049, 256, 0, stream>>>(features, enc_w1, enc_w2, dec_w2, mech_w1, mi_w2,
                                    dec_w1, featbf, w1p, ew2p, dw2p, mw1p, mw2p, dw1p,
                                    log_w, Abuf, accums);
    k_encf<<<256, 256, 0, stream>>>(featbf, w1p, enc_b1, ew2p, enc_b2, eps,
                                    out + 131072, out + 262144, zt, accums);
    k_mimech<<<4032, 256, 0, stream>>>(zt, mi_w1, mi_b1, mw2p, mi_b2, mi_w3, accums + 4,
                                       Abuf, mw1p, mech_b1, mech_w2, mech_b2, out);
    k_decf<<<dim3(128, 4), 256, 0, stream>>>(out, dw1p, dec_b1, dw2p, dec_b2, features,
                                             out + 393216, accums);
    k_final<<<1, 512, 0, stream>>>(accums, log_w, mi_b3, out + 2490368);
}